// Round 6
// baseline (964.531 us; speedup 1.0000x reference)
//
#include <hip/hip_runtime.h>

#define NB 8192
#define NT 1024
#define NH 10

__device__ __forceinline__ float rcpf(float x) { return __builtin_amdgcn_rcpf(x); }
__device__ __forceinline__ float sigm(float x) { return rcpf(1.0f + __expf(-x)); }
__device__ __forceinline__ float tanhx(float x) { return 1.0f - 2.0f * rcpf(__expf(2.0f * x) + 1.0f); }
__device__ __forceinline__ float bperm(int addr, float v) {
    return __int_as_float(__builtin_amdgcn_ds_bpermute(addr, __float_as_int(v)));
}

// 10 lanes per row-pair-group; lane j owns hidden index j (gate rows j, j+10, j+20)
// for TWO batch rows A and B. 4 groups/wave (lanes 40-63 idle) -> 8 rows/wave.
// 1024 waves total = exactly 1 wave/SIMD; 256 blocks = 1 block/CU.
// Per-timestep overhead (weight reloads, broadcast, loop) is amortized over 2 rows,
// and the two independent recurrence chains per lane provide the ILP that replaces TLP.
__attribute__((amdgpu_waves_per_eu(1, 1)))
__global__ __launch_bounds__(256) void gru_fused(
    const float* __restrict__ X,
    const float* __restrict__ Wih0, const float* __restrict__ Whh0,
    const float* __restrict__ bih0, const float* __restrict__ bhh0,
    const float* __restrict__ Wih1, const float* __restrict__ Whh1,
    const float* __restrict__ bih1, const float* __restrict__ bhh1,
    const float* __restrict__ Wfc,  const float* __restrict__ bfc,
    float* __restrict__ out)
{
    const int tid  = threadIdx.x;
    const int lane = tid & 63;
    const int wv   = tid >> 6;
    const int g    = lane / 10;      // 0..3 active, 4..6 idle mirrors
    const int j    = lane - g * 10;  // 0..9: hidden index
    const bool active = (g < 4);
    const int gg   = active ? g : 0;
    const int base = gg * 10;

    const int bA = blockIdx.x * 32 + wv * 8 + gg;  // rows A: group g
    const int bB = bA + 4;                         // rows B: group g + 4

    const int r0 = j, r1 = j + 10, r2 = j + 20;

    // ---- weights as scalars (unrolled arrays) ----
    const float wxr0 = Wih0[r0 * 2], wxr1 = Wih0[r0 * 2 + 1];
    const float wxz0 = Wih0[r1 * 2], wxz1 = Wih0[r1 * 2 + 1];
    const float wxn0 = Wih0[r2 * 2], wxn1 = Wih0[r2 * 2 + 1];

    float whr0[NH], whz0[NH], whn0[NH];
    float wir1[NH], wiz1[NH], win1[NH];
    float whr1[NH], whz1[NH], whn1[NH];
#pragma unroll
    for (int k = 0; k < NH; ++k) {
        whr0[k] = Whh0[r0 * NH + k]; whz0[k] = Whh0[r1 * NH + k]; whn0[k] = Whh0[r2 * NH + k];
        wir1[k] = Wih1[r0 * NH + k]; wiz1[k] = Wih1[r1 * NH + k]; win1[k] = Wih1[r2 * NH + k];
        whr1[k] = Whh1[r0 * NH + k]; whz1[k] = Whh1[r1 * NH + k]; whn1[k] = Whh1[r2 * NH + k];
    }
    const float br0  = bih0[r0] + bhh0[r0];
    const float bz0  = bih0[r1] + bhh0[r1];
    const float bxn0 = bih0[r2];
    const float bhn0 = bhh0[r2];
    const float br1  = bih1[r0] + bhh1[r0];
    const float bz1  = bih1[r1] + bhh1[r1];
    const float bxn1 = bih1[r2];
    const float bhn1 = bhh1[r2];

    const int ad0 = base << 2;  // bperm byte base; +4k folds into offset field

    // ---- state: replicated h (scalar arrays) + own element, for rows A and B ----
    float h0A[NH], h1A[NH], h0B[NH], h1B[NH];
#pragma unroll
    for (int k = 0; k < NH; ++k) { h0A[k] = h1A[k] = h0B[k] = h1B[k] = 0.0f; }
    float my0A = 0.0f, my1A = 0.0f, my0B = 0.0f, my1B = 0.0f;

    const float2* xpA = reinterpret_cast<const float2*>(X) + (size_t)bA * NT;
    const float2* xpB = reinterpret_cast<const float2*>(X) + (size_t)bB * NT;
    float2 xA = xpA[0], xB = xpB[0];
    float2 xA_n, xB_n;

#define GRU_STEP(PREFETCH, T)                                                      \
    do {                                                                           \
        if (PREFETCH) { xA_n = xpA[(T) + 1]; xB_n = xpB[(T) + 1]; }                \
        /* ---------- layer 0, rows A & B ---------- */                            \
        float prA = br0 + wxr0 * xA.x + wxr1 * xA.y;                               \
        float pzA = bz0 + wxz0 * xA.x + wxz1 * xA.y;                               \
        float pxA = bxn0 + wxn0 * xA.x + wxn1 * xA.y;                              \
        float phA = bhn0;                                                          \
        float prB = br0 + wxr0 * xB.x + wxr1 * xB.y;                               \
        float pzB = bz0 + wxz0 * xB.x + wxz1 * xB.y;                               \
        float pxB = bxn0 + wxn0 * xB.x + wxn1 * xB.y;                              \
        float phB = bhn0;                                                          \
        _Pragma("unroll")                                                          \
        for (int k = 0; k < NH; ++k) {                                             \
            prA += whr0[k] * h0A[k]; pzA += whz0[k] * h0A[k]; phA += whn0[k] * h0A[k]; \
            prB += whr0[k] * h0B[k]; pzB += whz0[k] * h0B[k]; phB += whn0[k] * h0B[k]; \
        }                                                                          \
        {                                                                          \
            const float rA = sigm(prA), zA = sigm(pzA);                            \
            const float nA = tanhx(pxA + rA * phA);                                \
            my0A = nA + zA * (my0A - nA);                                          \
            const float rB = sigm(prB), zB = sigm(pzB);                            \
            const float nB = tanhx(pxB + rB * phB);                                \
            my0B = nB + zB * (my0B - nB);                                          \
        }                                                                          \
        _Pragma("unroll")                                                          \
        for (int k = 0; k < NH; ++k) {                                             \
            h0A[k] = bperm(ad0 + 4 * k, my0A);                                     \
            h0B[k] = bperm(ad0 + 4 * k, my0B);                                     \
        }                                                                          \
        /* ---------- layer 1, rows A & B ---------- */                            \
        float qrA = br1, qzA = bz1, qxA = bxn1, qhA = bhn1;                        \
        float qrB = br1, qzB = bz1, qxB = bxn1, qhB = bhn1;                        \
        _Pragma("unroll")                                                          \
        for (int k = 0; k < NH; ++k) {                                             \
            qrA += wir1[k] * h0A[k]; qzA += wiz1[k] * h0A[k]; qxA += win1[k] * h0A[k]; \
            qrB += wir1[k] * h0B[k]; qzB += wiz1[k] * h0B[k]; qxB += win1[k] * h0B[k]; \
        }                                                                          \
        _Pragma("unroll")                                                          \
        for (int k = 0; k < NH; ++k) {                                             \
            qrA += whr1[k] * h1A[k]; qzA += whz1[k] * h1A[k]; qhA += whn1[k] * h1A[k]; \
            qrB += whr1[k] * h1B[k]; qzB += whz1[k] * h1B[k]; qhB += whn1[k] * h1B[k]; \
        }                                                                          \
        {                                                                          \
            const float rA = sigm(qrA), zA = sigm(qzA);                            \
            const float nA = tanhx(qxA + rA * qhA);                                \
            my1A = nA + zA * (my1A - nA);                                          \
            const float rB = sigm(qrB), zB = sigm(qzB);                            \
            const float nB = tanhx(qxB + rB * qhB);                                \
            my1B = nB + zB * (my1B - nB);                                          \
        }                                                                          \
        _Pragma("unroll")                                                          \
        for (int k = 0; k < NH; ++k) {                                             \
            h1A[k] = bperm(ad0 + 4 * k, my1A);                                     \
            h1B[k] = bperm(ad0 + 4 * k, my1B);                                     \
        }                                                                          \
        if (PREFETCH) { xA = xA_n; xB = xB_n; }                                    \
    } while (0)

    for (int t = 0; t < NT - 1; ++t) {
        GRU_STEP(true, t);
    }
    GRU_STEP(false, NT - 1);  // peeled last step: no prefetch, no OOB

#undef GRU_STEP

    // ---------- FC head: o = 0,1 on lanes j = 0,1 of each active group ----------
    if (active && j < 2) {
        float accA = bfc[j], accB = bfc[j];
#pragma unroll
        for (int k = 0; k < NH; ++k) {
            const float w = Wfc[j * NH + k];
            accA += w * h1A[k];
            accB += w * h1B[k];
        }
        out[(size_t)bA * 2 + j] = accA;
        out[(size_t)bB * 2 + j] = accB;
    }
}

extern "C" void kernel_launch(void* const* d_in, const int* in_sizes, int n_in,
                              void* d_out, int out_size, void* d_ws, size_t ws_size,
                              hipStream_t stream) {
    const float* X    = (const float*)d_in[0];
    const float* Wih0 = (const float*)d_in[1];
    const float* Whh0 = (const float*)d_in[2];
    const float* bih0 = (const float*)d_in[3];
    const float* bhh0 = (const float*)d_in[4];
    const float* Wih1 = (const float*)d_in[5];
    const float* Whh1 = (const float*)d_in[6];
    const float* bih1 = (const float*)d_in[7];
    const float* bhh1 = (const float*)d_in[8];
    const float* Wfc  = (const float*)d_in[9];
    const float* bfc  = (const float*)d_in[10];
    float* out = (float*)d_out;

    const int grid = NB / 32;  // 256 blocks x 4 waves x 8 rows = 8192 rows; 1 block/CU
    gru_fused<<<grid, 256, 0, stream>>>(X, Wih0, Whh0, bih0, bhh0,
                                        Wih1, Whh1, bih1, bhh1, Wfc, bfc, out);
}

// Round 7
// 717.851 us; speedup vs baseline: 1.3436x; 1.3436x over previous
//
#include <hip/hip_runtime.h>

#define NB 8192
#define NT 1024
#define NH 10
#define ROWS_PER_WAVE 4     // 10 lanes/row, lanes 40..63 idle
#define ROWS_PER_BLOCK 16   // 4 waves/block
typedef float v2f __attribute__((ext_vector_type(2)));

__device__ __forceinline__ float rcpf(float x) { return __builtin_amdgcn_rcpf(x); }
__device__ __forceinline__ float bperm(int addr, float v) {
    return __int_as_float(__builtin_amdgcn_ds_bpermute(addr, __float_as_int(v)));
}
__device__ __forceinline__ float hsum(v2f a) { return a.x + a.y; }

// Explicit packed fp32 FMA (gfx90a+/gfx950 full-rate, 2 lanes-worth per issue).
// Forced via asm: R1-R5 evidence suggests the backend scalarized the v2f math
// (445 issue-cyc/t decomposes exactly as scalar-FMA + quarter-rate trans).
__device__ __forceinline__ v2f pkfma(v2f a, v2f b, v2f c) {
    v2f d;
    asm("v_pk_fma_f32 %0, %1, %2, %3" : "=v"(d) : "v"(a), "v"(b), "v"(c));
    return d;
}
__device__ __forceinline__ v2f pkmul(v2f a, v2f b) {
    v2f d;
    asm("v_pk_mul_f32 %0, %1, %2" : "=v"(d) : "v"(a), "v"(b));
    return d;
}

// two sigmoids, ONE v_rcp: R = 1/(dr*dz); sig(pr)=dz*R, sig(pz)=dr*R.
// Safe: |p| <= ~7 at these weight scales, so d in [1+e^-7, 1+e^7], no overflow.
__device__ __forceinline__ void sigm2(float pr, float pz, float& r, float& z) {
    const float dr = 1.0f + __expf(-pr);
    const float dz = 1.0f + __expf(-pz);
    const float R = rcpf(dr * dz);
    r = dz * R;
    z = dr * R;
}
__device__ __forceinline__ float tanhx(float x) { return 1.0f - 2.0f * rcpf(__expf(2.0f * x) + 1.0f); }

__attribute__((amdgpu_waves_per_eu(2, 2)))
__global__ __launch_bounds__(256) void gru_fused(
    const float* __restrict__ X,
    const float* __restrict__ Wih0, const float* __restrict__ Whh0,
    const float* __restrict__ bih0, const float* __restrict__ bhh0,
    const float* __restrict__ Wih1, const float* __restrict__ Whh1,
    const float* __restrict__ b_ih1, const float* __restrict__ b_hh1,
    const float* __restrict__ Wfc,  const float* __restrict__ bfc,
    float* __restrict__ out)
{
    const int tid  = threadIdx.x;
    const int lane = tid & 63;
    const int wave = tid >> 6;
    const int g    = lane / 10;      // group in wave: 0..3 real, 4..6 idle
    const int j    = lane - g * 10;  // 0..9: this lane's hidden/gate index
    const int base = g * 10;

    const bool active = (g < ROWS_PER_WAVE);
    int b = blockIdx.x * ROWS_PER_BLOCK + wave * ROWS_PER_WAVE + (active ? g : 0);
    const bool store_ok = active && (b < NB);
    if (b >= NB) b = NB - 1;

    const int r0 = j, r1 = j + 10, r2 = j + 20;

    // ---- per-lane weights, packed as float2 pairs ----
    v2f wxr = *reinterpret_cast<const v2f*>(Wih0 + r0 * 2);
    v2f wxz = *reinterpret_cast<const v2f*>(Wih0 + r1 * 2);
    v2f wxn = *reinterpret_cast<const v2f*>(Wih0 + r2 * 2);

    v2f whr0[5], whz0[5], whn0[5];
    v2f wir1[5], wiz1[5], win1[5];
    v2f whr1[5], whz1[5], whn1[5];
#pragma unroll
    for (int k = 0; k < 5; ++k) {
        whr0[k] = *reinterpret_cast<const v2f*>(Whh0 + r0 * NH + 2 * k);
        whz0[k] = *reinterpret_cast<const v2f*>(Whh0 + r1 * NH + 2 * k);
        whn0[k] = *reinterpret_cast<const v2f*>(Whh0 + r2 * NH + 2 * k);
        wir1[k] = *reinterpret_cast<const v2f*>(Wih1 + r0 * NH + 2 * k);
        wiz1[k] = *reinterpret_cast<const v2f*>(Wih1 + r1 * NH + 2 * k);
        win1[k] = *reinterpret_cast<const v2f*>(Wih1 + r2 * NH + 2 * k);
        whr1[k] = *reinterpret_cast<const v2f*>(Whh1 + r0 * NH + 2 * k);
        whz1[k] = *reinterpret_cast<const v2f*>(Whh1 + r1 * NH + 2 * k);
        whn1[k] = *reinterpret_cast<const v2f*>(Whh1 + r2 * NH + 2 * k);
    }
    const float br0  = bih0[r0] + bhh0[r0];
    const float bz0  = bih0[r1] + bhh0[r1];
    const float bxn0 = bih0[r2];
    const float bhn0 = bhh0[r2];
    const float br1  = b_ih1[r0] + b_hh1[r0];
    const float bz1  = b_ih1[r1] + b_hh1[r1];
    const float bxn1 = b_ih1[r2];
    const float bhn1 = b_hh1[r2];

    const int ad0 = base << 2;  // bperm byte base; +const folds into offset field

    v2f h0p[5], h1p[5];
#pragma unroll
    for (int k = 0; k < 5; ++k) { h0p[k] = (v2f){0.f, 0.f}; h1p[k] = (v2f){0.f, 0.f}; }
    float my_h0 = 0.0f, my_h1 = 0.0f;

    const float2* xp = reinterpret_cast<const float2*>(X) + (size_t)b * NT;
    float2 xc = xp[0];

    for (int t = 0; t < NT; ++t) {
        const float2 xnext = xp[(t + 1 < NT) ? (t + 1) : (NT - 1)];
        const v2f xv = {xc.x, xc.y};

        // ---------- layer 0 ----------
        v2f ar = pkmul(wxr, xv);
        v2f az = pkmul(wxz, xv);
        v2f anx = pkmul(wxn, xv);
        v2f anh = (v2f){0.f, 0.f};
#pragma unroll
        for (int k = 0; k < 5; ++k) {
            ar  = pkfma(whr0[k], h0p[k], ar);
            az  = pkfma(whz0[k], h0p[k], az);
            anh = pkfma(whn0[k], h0p[k], anh);
        }
        float r, z;
        sigm2(br0 + hsum(ar), bz0 + hsum(az), r, z);
        const float n = tanhx(bxn0 + hsum(anx) + r * (bhn0 + hsum(anh)));
        my_h0 = n + z * (my_h0 - n);
#pragma unroll
        for (int k = 0; k < 5; ++k) {
            h0p[k].x = bperm(ad0 + 8 * k,     my_h0);
            h0p[k].y = bperm(ad0 + 8 * k + 4, my_h0);
        }

        // ---------- layer 1 ----------
        v2f a1r = (v2f){0.f, 0.f}, a1z = (v2f){0.f, 0.f};
        v2f a1n = (v2f){0.f, 0.f}, a1h = (v2f){0.f, 0.f};
#pragma unroll
        for (int k = 0; k < 5; ++k) {
            a1r = pkfma(wir1[k], h0p[k], a1r);
            a1z = pkfma(wiz1[k], h0p[k], a1z);
            a1n = pkfma(win1[k], h0p[k], a1n);
        }
#pragma unroll
        for (int k = 0; k < 5; ++k) {
            a1r = pkfma(whr1[k], h1p[k], a1r);
            a1z = pkfma(whz1[k], h1p[k], a1z);
            a1h = pkfma(whn1[k], h1p[k], a1h);
        }
        float rr1, zz1;
        sigm2(br1 + hsum(a1r), bz1 + hsum(a1z), rr1, zz1);
        const float n1 = tanhx(bxn1 + hsum(a1n) + rr1 * (bhn1 + hsum(a1h)));
        my_h1 = n1 + zz1 * (my_h1 - n1);
#pragma unroll
        for (int k = 0; k < 5; ++k) {
            h1p[k].x = bperm(ad0 + 8 * k,     my_h1);
            h1p[k].y = bperm(ad0 + 8 * k + 4, my_h1);
        }

        xc = xnext;
    }

    // ---------- FC head ----------
    if (store_ok && j < 2) {
        float acc = bfc[j];
#pragma unroll
        for (int k = 0; k < 5; ++k)
            acc += Wfc[j * NH + 2 * k] * h1p[k].x + Wfc[j * NH + 2 * k + 1] * h1p[k].y;
        out[(size_t)b * 2 + j] = acc;
    }
}

extern "C" void kernel_launch(void* const* d_in, const int* in_sizes, int n_in,
                              void* d_out, int out_size, void* d_ws, size_t ws_size,
                              hipStream_t stream) {
    const float* X    = (const float*)d_in[0];
    const float* Wih0 = (const float*)d_in[1];
    const float* Whh0 = (const float*)d_in[2];
    const float* bih0 = (const float*)d_in[3];
    const float* bhh0 = (const float*)d_in[4];
    const float* Wih1 = (const float*)d_in[5];
    const float* Whh1 = (const float*)d_in[6];
    const float* bih1 = (const float*)d_in[7];
    const float* bhh1 = (const float*)d_in[8];
    const float* Wfc  = (const float*)d_in[9];
    const float* bfc  = (const float*)d_in[10];
    float* out = (float*)d_out;

    const int grid = NB / ROWS_PER_BLOCK;  // 512 blocks -> 2048 waves = 2/SIMD exactly
    gru_fused<<<grid, 256, 0, stream>>>(X, Wih0, Whh0, bih0, bhh0,
                                        Wih1, Whh1, bih1, bhh1, Wfc, bfc, out);
}